// Round 2
// baseline (1667.489 us; speedup 1.0000x reference)
//
#include <hip/hip_runtime.h>
#include <hip/hip_bf16.h>

typedef __hip_bfloat16 bf16;

#define HW   65536
#define WID  256
#define CC   96
#define NB   4
static const size_t S_ELEMS = (size_t)NB * CC * HW;  // 25,165,824 elements

__device__ __forceinline__ float lo2f(unsigned u) { unsigned x = u << 16;        return __builtin_bit_cast(float, x); }
__device__ __forceinline__ float hi2f(unsigned u) { unsigned x = u & 0xffff0000u; return __builtin_bit_cast(float, x); }
__device__ __forceinline__ float b2f(bf16 v) { return __bfloat162float(v); }

__device__ __forceinline__ void load8f(const float* p, float v[8]) {
    float4 a = *reinterpret_cast<const float4*>(p);
    float4 b = *reinterpret_cast<const float4*>(p + 4);
    v[0] = a.x; v[1] = a.y; v[2] = a.z; v[3] = a.w;
    v[4] = b.x; v[5] = b.y; v[6] = b.z; v[7] = b.w;
}
__device__ __forceinline__ void load8b(const bf16* p, float v[8]) {
    uint4 u = *reinterpret_cast<const uint4*>(p);
    v[0] = lo2f(u.x); v[1] = hi2f(u.x); v[2] = lo2f(u.y); v[3] = hi2f(u.y);
    v[4] = lo2f(u.z); v[5] = hi2f(u.z); v[6] = lo2f(u.w); v[7] = hi2f(u.w);
}
__device__ __forceinline__ void store8b(bf16* p, const float v[8]) {
    alignas(16) bf16 o[8];
#pragma unroll
    for (int i = 0; i < 8; ++i) o[i] = __float2bfloat16(v[i]);
    *reinterpret_cast<uint4*>(p) = *reinterpret_cast<const uint4*>(o);
}
__device__ __forceinline__ void store8f(float* p, const float v[8]) {
    *reinterpret_cast<float4*>(p)     = make_float4(v[0], v[1], v[2], v[3]);
    *reinterpret_cast<float4*>(p + 4) = make_float4(v[4], v[5], v[6], v[7]);
}

// ---------------- Kernel 1: LayerNorm over channel dim of NCHW ----------------
// fp32 in, bf16 out. 8 positions/thread, 2 passes over C. grid = 512 x 64.
__global__ __launch_bounds__(64) void ln_kernel(
    const float* __restrict__ x, const float* __restrict__ lw,
    const float* __restrict__ lb, bf16* __restrict__ y)
{
    int t  = blockIdx.x * 64 + threadIdx.x;    // [0, 32768)
    int b  = t >> 13;
    int hw = (t & 8191) * 8;
    size_t base = (size_t)b * CC * HW + hw;

    float s[8], q[8];
#pragma unroll
    for (int i = 0; i < 8; ++i) { s[i] = 0.f; q[i] = 0.f; }

    for (int c = 0; c < CC; ++c) {
        float v[8]; load8f(&x[base + (size_t)c * HW], v);
#pragma unroll
        for (int i = 0; i < 8; ++i) { s[i] += v[i]; q[i] += v[i] * v[i]; }
    }
    float mu[8], rs[8];
#pragma unroll
    for (int i = 0; i < 8; ++i) {
        mu[i] = s[i] * (1.f / 96.f);
        float var = q[i] * (1.f / 96.f) - mu[i] * mu[i];
        rs[i] = rsqrtf(var + 1e-6f);
    }
    for (int c = 0; c < CC; ++c) {
        float v[8]; load8f(&x[base + (size_t)c * HW], v);
        float g = lw[c], be = lb[c];
        float o[8];
#pragma unroll
        for (int i = 0; i < 8; ++i) o[i] = (v[i] - mu[i]) * rs[i] * g + be;
        store8b(&y[base + (size_t)c * HW], o);
    }
}

// ---------------- conv1x1 (pointwise GEMM): out[o,p] = sum_c w[o,c]*in[c,p] ----------------
// 64 positions/block, all COUT channels. 256 threads as (tx in [0,32), ty in [0,8)).
// LDS holds bf16 input tile + bf16 transposed weights; fp32 accumulate.
template <typename TI, typename TO, int CIN, int COUT, bool GELU, bool HASRES>
__global__ __launch_bounds__(256) void conv1x1_kernel(
    const TI* __restrict__ in, const float* __restrict__ wgt,
    const float* __restrict__ bias, const float* __restrict__ resid,
    TO* __restrict__ out)
{
    constexpr int T  = 64;
    constexpr int TO_ = COUT / 32;
    constexpr int WP = COUT + 2;   // pad -> conflict-free transposed weight access
    __shared__ alignas(16) bf16 s_in[CIN * T];
    __shared__ alignas(16) bf16 s_w[CIN * WP];

    const int tid  = threadIdx.x;
    const int pos0 = blockIdx.x * T;
    const int b    = pos0 >> 16;
    const int hw0  = pos0 & 65535;
    const size_t ibase = (size_t)b * CIN * HW + hw0;

    // weights: global fp32 [COUT][CIN] -> LDS bf16 transposed [CIN][WP]
    for (int k = tid; k < CIN * COUT; k += 256) {
        int o = k / CIN, c = k - o * CIN;
        s_w[c * WP + o] = __float2bfloat16(wgt[k]);
    }
    // input tile: CIN rows x 64 positions, 8 elems per iteration
    for (int k = tid; k < CIN * 8; k += 256) {
        int c = k >> 3, ch = (k & 7) * 8;
        float v[8];
        if constexpr (__is_same(TI, float)) load8f(&in[ibase + (size_t)c * HW + ch], v);
        else                                load8b(&in[ibase + (size_t)c * HW + ch], v);
        store8b(&s_in[c * T + ch], v);
    }
    __syncthreads();

    const int tx = tid & 31, ty = tid >> 5;
    float acc[TO_][8];
#pragma unroll
    for (int a = 0; a < TO_; ++a)
#pragma unroll
        for (int i = 0; i < 8; ++i) acc[a][i] = 0.f;

    for (int c = 0; c < CIN; ++c) {
        float a[8]; load8b(&s_in[c * T + ty * 8], a);
#pragma unroll
        for (int oo = 0; oo < TO_; ++oo) {
            float wv = b2f(s_w[c * WP + tx * TO_ + oo]);
#pragma unroll
            for (int i = 0; i < 8; ++i) acc[oo][i] += wv * a[i];
        }
    }

    const size_t obase = (size_t)b * COUT * HW + hw0 + ty * 8;
#pragma unroll
    for (int oo = 0; oo < TO_; ++oo) {
        int o = tx * TO_ + oo;
        float bv = bias[o];
        float r[8];
        if (HASRES) load8f(&resid[obase + (size_t)o * HW], r);
        float ov[8];
#pragma unroll
        for (int i = 0; i < 8; ++i) {
            float v = acc[oo][i] + bv;
            if (GELU) v = 0.5f * v * (1.f + erff(v * 0.70710678118654752f));
            if (HASRES) v += r[i];
            ov[i] = v;
        }
        if constexpr (__is_same(TO, float)) store8f(&out[obase + (size_t)o * HW], ov);
        else                                store8b(&out[obase + (size_t)o * HW], ov);
    }
}

// ---------------- Kernel 3: three depthwise experts + soft combine ----------------
// e0: 3x3 d=1 on t0; e1: 3x3 d=2 on xn; e2: 5x5 d=3 on xn. One output/thread.
// All threads in a block share (b,c) -> weight loads are wave-uniform (SGPR).
__global__ __launch_bounds__(256) void experts_kernel(
    const bf16* __restrict__ xn, const bf16* __restrict__ t0,
    const float* __restrict__ w0, const float* __restrict__ b0,
    const float* __restrict__ w1, const float* __restrict__ b1,
    const float* __restrict__ w2, const float* __restrict__ b2,
    const float* __restrict__ sw, const float* __restrict__ prompt,
    bf16* __restrict__ xa)
{
    int idx = blockIdx.x * 256 + threadIdx.x;   // [0, 25165824)
    int hw  = idx & 65535;
    int bc  = idx >> 16;                        // b*96 + c
    int b   = bc / 96;
    int c   = bc - b * 96;
    int h   = hw >> 8;
    int w   = hw & 255;
    size_t pbase = (size_t)bc * HW;

    float a0 = b0[c];
#pragma unroll
    for (int kh = 0; kh < 3; ++kh) {
        int hh = h + kh - 1;
#pragma unroll
        for (int kw = 0; kw < 3; ++kw) {
            int ww = w + kw - 1;
            bool ok = ((unsigned)hh < 256u) & ((unsigned)ww < 256u);
            float v = ok ? b2f(t0[pbase + hh * WID + ww]) : 0.f;
            a0 += v * w0[c * 9 + kh * 3 + kw];
        }
    }
    float a1 = b1[c];
#pragma unroll
    for (int kh = 0; kh < 3; ++kh) {
        int hh = h + (kh - 1) * 2;
#pragma unroll
        for (int kw = 0; kw < 3; ++kw) {
            int ww = w + (kw - 1) * 2;
            bool ok = ((unsigned)hh < 256u) & ((unsigned)ww < 256u);
            float v = ok ? b2f(xn[pbase + hh * WID + ww]) : 0.f;
            a1 += v * w1[c * 9 + kh * 3 + kw];
        }
    }
    float a2 = b2[c];
#pragma unroll
    for (int kh = 0; kh < 5; ++kh) {
        int hh = h + (kh - 2) * 3;
#pragma unroll
        for (int kw = 0; kw < 5; ++kw) {
            int ww = w + (kw - 2) * 3;
            bool ok = ((unsigned)hh < 256u) & ((unsigned)ww < 256u);
            float v = ok ? b2f(xn[pbase + hh * WID + ww]) : 0.f;
            a2 += v * w2[c * 25 + kh * 5 + kw];
        }
    }

    float s0 = sw[b * 3 + 0], s1 = sw[b * 3 + 1], s2 = sw[b * 3 + 2];
    float pr = 1.f + prompt[b * 96 + c];
    xa[idx] = __float2bfloat16((s0 * a0 + s1 * a1 + s2 * a2) * pr);
}

// ---------------- launch ----------------
extern "C" void kernel_launch(void* const* d_in, const int* in_sizes, int n_in,
                              void* d_out, int out_size, void* d_ws, size_t ws_size,
                              hipStream_t stream)
{
    const float* x       = (const float*)d_in[0];
    const float* prompt  = (const float*)d_in[1];
    const float* sw      = (const float*)d_in[2];
    const float* ln_w    = (const float*)d_in[3];
    const float* ln_b    = (const float*)d_in[4];
    const float* e0_pw_w = (const float*)d_in[5];
    const float* e0_pw_b = (const float*)d_in[6];
    const float* e0_dw_w = (const float*)d_in[7];
    const float* e0_dw_b = (const float*)d_in[8];
    const float* e1_dw_w = (const float*)d_in[9];
    const float* e1_dw_b = (const float*)d_in[10];
    const float* e2_dw_w = (const float*)d_in[11];
    const float* e2_dw_b = (const float*)d_in[12];
    const float* proj_w  = (const float*)d_in[13];
    const float* proj_b  = (const float*)d_in[14];
    const float* ffn1_w  = (const float*)d_in[15];
    const float* ffn1_b  = (const float*)d_in[16];
    const float* ffn2_w  = (const float*)d_in[17];
    const float* ffn2_b  = (const float*)d_in[18];

    float* out = (float*)d_out;                 // x1 lives here fp32 between k4..k6
    bf16*  ws  = (bf16*)d_ws;
    bf16*  A   = ws;                 // xn  bf16 (48 MB)
    bf16*  Bt  = ws + S_ELEMS;       // t0  bf16 (48 MB)
    bf16*  Cx  = ws + 2 * S_ELEMS;   // xa  bf16 (48 MB)  -> peak ws = 144 MB
    bf16*  E   = ws;                 // h (192 ch) bf16 (96 MB), reuses A+Bt once dead

    // 1) xn = LayerNorm_c(x)
    ln_kernel<<<512, 64, 0, stream>>>(x, ln_w, ln_b, A);
    // 2) t0 = conv1x1(xn, e0_pw)
    conv1x1_kernel<bf16, bf16, 96, 96, false, false>
        <<<4096, 256, 0, stream>>>(A, e0_pw_w, e0_pw_b, nullptr, Bt);
    // 3) xa = (s0*dw3(t0) + s1*dw3d2(xn) + s2*dw5d3(xn)) * (1+prompt)
    experts_kernel<<<98304, 256, 0, stream>>>(A, Bt, e0_dw_w, e0_dw_b, e1_dw_w, e1_dw_b,
                                              e2_dw_w, e2_dw_b, sw, prompt, Cx);
    // 4) x1 = x + conv1x1(xa, proj)  -> d_out (fp32)
    conv1x1_kernel<bf16, float, 96, 96, false, true>
        <<<4096, 256, 0, stream>>>(Cx, proj_w, proj_b, x, out);
    // 5) h = gelu(conv1x1(x1, ffn1)) -> E (bf16)
    conv1x1_kernel<float, bf16, 96, 192, true, false>
        <<<4096, 256, 0, stream>>>(out, ffn1_w, ffn1_b, nullptr, E);
    // 6) out = x1 + conv1x1(h, ffn2) -> d_out (in-place, per-thread same-address RMW)
    conv1x1_kernel<bf16, float, 192, 96, false, true>
        <<<4096, 256, 0, stream>>>(E, ffn2_w, ffn2_b, out, out);
}

// Round 3
// 918.809 us; speedup vs baseline: 1.8148x; 1.8148x over previous
//
#include <hip/hip_runtime.h>
#include <hip/hip_bf16.h>

typedef __hip_bfloat16 bf16;

#define HW   65536
#define WID  256
#define CC   96
#define NB   4
static const size_t S_ELEMS = (size_t)NB * CC * HW;  // 25,165,824 elements

__device__ __forceinline__ float lo2f(unsigned u) { unsigned x = u << 16;        return __builtin_bit_cast(float, x); }
__device__ __forceinline__ float hi2f(unsigned u) { unsigned x = u & 0xffff0000u; return __builtin_bit_cast(float, x); }
__device__ __forceinline__ float b2f(bf16 v) { return __bfloat162float(v); }

__device__ __forceinline__ void load8f(const float* p, float v[8]) {
    float4 a = *reinterpret_cast<const float4*>(p);
    float4 b = *reinterpret_cast<const float4*>(p + 4);
    v[0] = a.x; v[1] = a.y; v[2] = a.z; v[3] = a.w;
    v[4] = b.x; v[5] = b.y; v[6] = b.z; v[7] = b.w;
}
__device__ __forceinline__ void load8b(const bf16* p, float v[8]) {
    uint4 u = *reinterpret_cast<const uint4*>(p);
    v[0] = lo2f(u.x); v[1] = hi2f(u.x); v[2] = lo2f(u.y); v[3] = hi2f(u.y);
    v[4] = lo2f(u.z); v[5] = hi2f(u.z); v[6] = lo2f(u.w); v[7] = hi2f(u.w);
}
__device__ __forceinline__ void store8b(bf16* p, const float v[8]) {
    alignas(16) bf16 o[8];
#pragma unroll
    for (int i = 0; i < 8; ++i) o[i] = __float2bfloat16(v[i]);
    *reinterpret_cast<uint4*>(p) = *reinterpret_cast<const uint4*>(o);
}
__device__ __forceinline__ void store8f(float* p, const float v[8]) {
    *reinterpret_cast<float4*>(p)     = make_float4(v[0], v[1], v[2], v[3]);
    *reinterpret_cast<float4*>(p + 4) = make_float4(v[4], v[5], v[6], v[7]);
}

// ---------------- Kernel 1: LayerNorm over channel dim of NCHW ----------------
// fp32 in, bf16 out. 2 positions/thread -> 2048 waves (8/CU) for latency hiding.
__global__ __launch_bounds__(256) void ln_kernel(
    const float* __restrict__ x, const float* __restrict__ lw,
    const float* __restrict__ lb, bf16* __restrict__ y)
{
    int t  = blockIdx.x * 256 + threadIdx.x;   // [0, 131072)
    int b  = t >> 15;
    int hw = (t & 32767) * 2;
    size_t base = (size_t)b * CC * HW + hw;

    float s0 = 0.f, s1 = 0.f, q0 = 0.f, q1 = 0.f;
    for (int c = 0; c < CC; ++c) {
        float2 v = *reinterpret_cast<const float2*>(&x[base + (size_t)c * HW]);
        s0 += v.x; s1 += v.y; q0 += v.x * v.x; q1 += v.y * v.y;
    }
    float mu0 = s0 * (1.f / 96.f), mu1 = s1 * (1.f / 96.f);
    float rs0 = rsqrtf(q0 * (1.f / 96.f) - mu0 * mu0 + 1e-6f);
    float rs1 = rsqrtf(q1 * (1.f / 96.f) - mu1 * mu1 + 1e-6f);

    for (int c = 0; c < CC; ++c) {
        float2 v = *reinterpret_cast<const float2*>(&x[base + (size_t)c * HW]);
        float g = lw[c], be = lb[c];
        bf16 o[2];
        o[0] = __float2bfloat16((v.x - mu0) * rs0 * g + be);
        o[1] = __float2bfloat16((v.y - mu1) * rs1 * g + be);
        *reinterpret_cast<uint*>(&y[base + (size_t)c * HW]) = *reinterpret_cast<uint*>(o);
    }
}

// ---------------- conv1x1 (pointwise GEMM): out[o,p] = sum_c w[o,c]*in[c,p] ----------------
template <typename TI, typename TOT, int CIN, int COUT, bool GELU, bool HASRES>
__global__ __launch_bounds__(256) void conv1x1_kernel(
    const TI* __restrict__ in, const float* __restrict__ wgt,
    const float* __restrict__ bias, const float* __restrict__ resid,
    TOT* __restrict__ out)
{
    constexpr int T  = 64;
    constexpr int TO_ = COUT / 32;
    constexpr int WP = COUT + 2;
    __shared__ alignas(16) bf16 s_in[CIN * T];
    __shared__ alignas(16) bf16 s_w[CIN * WP];

    const int tid  = threadIdx.x;
    const int pos0 = blockIdx.x * T;
    const int b    = pos0 >> 16;
    const int hw0  = pos0 & 65535;
    const size_t ibase = (size_t)b * CIN * HW + hw0;

    for (int k = tid; k < CIN * COUT; k += 256) {
        int o = k / CIN, c = k - o * CIN;
        s_w[c * WP + o] = __float2bfloat16(wgt[k]);
    }
    for (int k = tid; k < CIN * 8; k += 256) {
        int c = k >> 3, ch = (k & 7) * 8;
        float v[8];
        if constexpr (__is_same(TI, float)) load8f(&in[ibase + (size_t)c * HW + ch], v);
        else                                load8b(&in[ibase + (size_t)c * HW + ch], v);
        store8b(&s_in[c * T + ch], v);
    }
    __syncthreads();

    const int tx = tid & 31, ty = tid >> 5;
    float acc[TO_][8];
#pragma unroll
    for (int a = 0; a < TO_; ++a)
#pragma unroll
        for (int i = 0; i < 8; ++i) acc[a][i] = 0.f;

    for (int c = 0; c < CIN; ++c) {
        float a[8]; load8b(&s_in[c * T + ty * 8], a);
#pragma unroll
        for (int oo = 0; oo < TO_; ++oo) {
            float wv = b2f(s_w[c * WP + tx * TO_ + oo]);
#pragma unroll
            for (int i = 0; i < 8; ++i) acc[oo][i] += wv * a[i];
        }
    }

    const size_t obase = (size_t)b * COUT * HW + hw0 + ty * 8;
#pragma unroll
    for (int oo = 0; oo < TO_; ++oo) {
        int o = tx * TO_ + oo;
        float bv = bias[o];
        float r[8];
        if (HASRES) load8f(&resid[obase + (size_t)o * HW], r);
        float ov[8];
#pragma unroll
        for (int i = 0; i < 8; ++i) {
            float v = acc[oo][i] + bv;
            if (GELU) v = 0.5f * v * (1.f + erff(v * 0.70710678118654752f));
            if (HASRES) v += r[i];
            ov[i] = v;
        }
        if constexpr (__is_same(TOT, float)) store8f(&out[obase + (size_t)o * HW], ov);
        else                                 store8b(&out[obase + (size_t)o * HW], ov);
    }
}

// ---------------- Kernel 3: experts, register-window stencil ----------------
// Thread computes 8 consecutive w outputs at one (b,c,h). Window [w0-8,w0+16)
// = 3 aligned 8-px chunks, each fully valid or fully OOB -> uniform predication.
// Rows from xn: {-6,-3,-2,0,2,3,6}; from t0: {-1,0,1}. Weights block-uniform.
__device__ __forceinline__ void load_win24(const bf16* rowp, int w0, bool rowok,
                                           float win[24])
{
    const uint4 z = make_uint4(0u, 0u, 0u, 0u);
    const uint4* p = reinterpret_cast<const uint4*>(rowp + w0 - 8);
    uint4 c0 = (rowok && (w0 >= 8))   ? p[0] : z;
    uint4 c1 =  rowok                 ? p[1] : z;
    uint4 c2 = (rowok && (w0 <= 240)) ? p[2] : z;
    win[0]=lo2f(c0.x); win[1]=hi2f(c0.x); win[2]=lo2f(c0.y); win[3]=hi2f(c0.y);
    win[4]=lo2f(c0.z); win[5]=hi2f(c0.z); win[6]=lo2f(c0.w); win[7]=hi2f(c0.w);
    win[8]=lo2f(c1.x); win[9]=hi2f(c1.x); win[10]=lo2f(c1.y); win[11]=hi2f(c1.y);
    win[12]=lo2f(c1.z); win[13]=hi2f(c1.z); win[14]=lo2f(c1.w); win[15]=hi2f(c1.w);
    win[16]=lo2f(c2.x); win[17]=hi2f(c2.x); win[18]=lo2f(c2.y); win[19]=hi2f(c2.y);
    win[20]=lo2f(c2.z); win[21]=hi2f(c2.z); win[22]=lo2f(c2.w); win[23]=hi2f(c2.w);
}
__device__ __forceinline__ void apply3(const float wk[3], int dil,
                                       const float win[24], float acc[8])
{
#pragma unroll
    for (int kw = 0; kw < 3; ++kw) {
        float wv = wk[kw];
        int d = (kw - 1) * dil;
#pragma unroll
        for (int o = 0; o < 8; ++o) acc[o] += wv * win[o + 8 + d];
    }
}
__device__ __forceinline__ void apply5(const float wk[5],
                                       const float win[24], float acc[8])
{
#pragma unroll
    for (int kw = 0; kw < 5; ++kw) {
        float wv = wk[kw];
        int d = (kw - 2) * 3;
#pragma unroll
        for (int o = 0; o < 8; ++o) acc[o] += wv * win[o + 8 + d];
    }
}

__global__ __launch_bounds__(256) void experts_kernel(
    const bf16* __restrict__ xn, const bf16* __restrict__ t0,
    const float* __restrict__ w0, const float* __restrict__ b0,
    const float* __restrict__ w1, const float* __restrict__ b1,
    const float* __restrict__ w2, const float* __restrict__ b2,
    const float* __restrict__ sw, const float* __restrict__ prompt,
    bf16* __restrict__ xa)
{
    // grid: NB*CC*32 blocks; block: 256 threads = 8 rows x 32 w-groups
    const int tid = threadIdx.x;
    const int wg  = tid & 31;           // w-group
    const int r   = tid >> 5;           // row within block's 8-row strip
    const int bid = blockIdx.x;
    const int h0  = (bid & 31) * 8;
    const int bc  = bid >> 5;           // b*96 + c
    const int b   = bc / 96;
    const int c   = bc - b * 96;
    const int h   = h0 + r;
    const int w0p = wg * 8;
    const size_t pbase = (size_t)bc * HW;

    // block-uniform weights -> scalar loads
    float wk0[9], wk1[9], wk2[25];
#pragma unroll
    for (int i = 0; i < 9; ++i)  wk0[i] = w0[c * 9 + i];
#pragma unroll
    for (int i = 0; i < 9; ++i)  wk1[i] = w1[c * 9 + i];
#pragma unroll
    for (int i = 0; i < 25; ++i) wk2[i] = w2[c * 25 + i];

    float acc0[8], acc1[8], acc2[8];
    {
        float bb0 = b0[c], bb1 = b1[c], bb2 = b2[c];
#pragma unroll
        for (int o = 0; o < 8; ++o) { acc0[o] = bb0; acc1[o] = bb1; acc2[o] = bb2; }
    }

    const bf16* xp = xn + pbase;
    const bf16* tp = t0 + pbase;
    float win[24];

    // xn rows: dr=-6 (e2 kh0), -3 (e2 kh1), -2 (e1 kh0), 0 (e1 kh1 + e2 kh2),
    //          2 (e1 kh2), 3 (e2 kh3), 6 (e2 kh4)
    {
        int hh = h - 6; bool ok = (unsigned)hh < 256u;
        load_win24(xp + hh * WID, w0p, ok, win); apply5(&wk2[0],  win, acc2);
    }
    {
        int hh = h - 3; bool ok = (unsigned)hh < 256u;
        load_win24(xp + hh * WID, w0p, ok, win); apply5(&wk2[5],  win, acc2);
    }
    {
        int hh = h - 2; bool ok = (unsigned)hh < 256u;
        load_win24(xp + hh * WID, w0p, ok, win); apply3(&wk1[0], 2, win, acc1);
    }
    {
        int hh = h;     bool ok = true;
        load_win24(xp + hh * WID, w0p, ok, win);
        apply3(&wk1[3], 2, win, acc1); apply5(&wk2[10], win, acc2);
    }
    {
        int hh = h + 2; bool ok = (unsigned)hh < 256u;
        load_win24(xp + hh * WID, w0p, ok, win); apply3(&wk1[6], 2, win, acc1);
    }
    {
        int hh = h + 3; bool ok = (unsigned)hh < 256u;
        load_win24(xp + hh * WID, w0p, ok, win); apply5(&wk2[15], win, acc2);
    }
    {
        int hh = h + 6; bool ok = (unsigned)hh < 256u;
        load_win24(xp + hh * WID, w0p, ok, win); apply5(&wk2[20], win, acc2);
    }
    // t0 rows: dr=-1,0,1 (e0, dilation 1)
    {
        int hh = h - 1; bool ok = (unsigned)hh < 256u;
        load_win24(tp + hh * WID, w0p, ok, win); apply3(&wk0[0], 1, win, acc0);
    }
    {
        load_win24(tp + h * WID, w0p, true, win); apply3(&wk0[3], 1, win, acc0);
    }
    {
        int hh = h + 1; bool ok = (unsigned)hh < 256u;
        load_win24(tp + hh * WID, w0p, ok, win); apply3(&wk0[6], 1, win, acc0);
    }

    float s0 = sw[b * 3 + 0], s1 = sw[b * 3 + 1], s2 = sw[b * 3 + 2];
    float pr = 1.f + prompt[b * 96 + c];
    float ov[8];
#pragma unroll
    for (int o = 0; o < 8; ++o)
        ov[o] = (s0 * acc0[o] + s1 * acc1[o] + s2 * acc2[o]) * pr;
    store8b(&xa[pbase + h * WID + w0p], ov);
}

// ---------------- launch ----------------
extern "C" void kernel_launch(void* const* d_in, const int* in_sizes, int n_in,
                              void* d_out, int out_size, void* d_ws, size_t ws_size,
                              hipStream_t stream)
{
    const float* x       = (const float*)d_in[0];
    const float* prompt  = (const float*)d_in[1];
    const float* sw      = (const float*)d_in[2];
    const float* ln_w    = (const float*)d_in[3];
    const float* ln_b    = (const float*)d_in[4];
    const float* e0_pw_w = (const float*)d_in[5];
    const float* e0_pw_b = (const float*)d_in[6];
    const float* e0_dw_w = (const float*)d_in[7];
    const float* e0_dw_b = (const float*)d_in[8];
    const float* e1_dw_w = (const float*)d_in[9];
    const float* e1_dw_b = (const float*)d_in[10];
    const float* e2_dw_w = (const float*)d_in[11];
    const float* e2_dw_b = (const float*)d_in[12];
    const float* proj_w  = (const float*)d_in[13];
    const float* proj_b  = (const float*)d_in[14];
    const float* ffn1_w  = (const float*)d_in[15];
    const float* ffn1_b  = (const float*)d_in[16];
    const float* ffn2_w  = (const float*)d_in[17];
    const float* ffn2_b  = (const float*)d_in[18];

    float* out = (float*)d_out;                 // x1 lives here fp32 between k4..k6
    bf16*  ws  = (bf16*)d_ws;
    bf16*  A   = ws;                 // xn  bf16 (48 MB)
    bf16*  Bt  = ws + S_ELEMS;       // t0  bf16 (48 MB)
    bf16*  Cx  = ws + 2 * S_ELEMS;   // xa  bf16 (48 MB)  -> peak ws = 144 MB
    bf16*  E   = ws;                 // h (192 ch) bf16 (96 MB), reuses A+Bt once dead

    // 1) xn = LayerNorm_c(x)
    ln_kernel<<<512, 256, 0, stream>>>(x, ln_w, ln_b, A);
    // 2) t0 = conv1x1(xn, e0_pw)
    conv1x1_kernel<bf16, bf16, 96, 96, false, false>
        <<<4096, 256, 0, stream>>>(A, e0_pw_w, e0_pw_b, nullptr, Bt);
    // 3) xa = (s0*dw3(t0) + s1*dw3d2(xn) + s2*dw5d3(xn)) * (1+prompt)
    experts_kernel<<<12288, 256, 0, stream>>>(A, Bt, e0_dw_w, e0_dw_b, e1_dw_w, e1_dw_b,
                                              e2_dw_w, e2_dw_b, sw, prompt, Cx);
    // 4) x1 = x + conv1x1(xa, proj)  -> d_out (fp32)
    conv1x1_kernel<bf16, float, 96, 96, false, true>
        <<<4096, 256, 0, stream>>>(Cx, proj_w, proj_b, x, out);
    // 5) h = gelu(conv1x1(x1, ffn1)) -> E (bf16)
    conv1x1_kernel<float, bf16, 96, 192, true, false>
        <<<4096, 256, 0, stream>>>(out, ffn1_w, ffn1_b, nullptr, E);
    // 6) out = x1 + conv1x1(h, ffn2) -> d_out (in-place, per-thread same-address RMW)
    conv1x1_kernel<bf16, float, 192, 96, false, true>
        <<<4096, 256, 0, stream>>>(E, ffn2_w, ffn2_b, out, out);
}

// Round 4
// 652.032 us; speedup vs baseline: 2.5574x; 1.4091x over previous
//
#include <hip/hip_runtime.h>
#include <hip/hip_bf16.h>

typedef __hip_bfloat16 bf16;
typedef __attribute__((ext_vector_type(8))) __bf16 bf16x8;
typedef __attribute__((ext_vector_type(4))) float  f32x4;

#define HW   65536
#define WID  256
#define CC   96
#define NB   4
static const size_t S_ELEMS = (size_t)NB * CC * HW;  // 25,165,824 elements

__device__ __forceinline__ float lo2f(unsigned u) { unsigned x = u << 16;        return __builtin_bit_cast(float, x); }
__device__ __forceinline__ float hi2f(unsigned u) { unsigned x = u & 0xffff0000u; return __builtin_bit_cast(float, x); }
__device__ __forceinline__ float b2f(bf16 v) { return __bfloat162float(v); }
__device__ __forceinline__ unsigned short f2bu(float f) {
    return __builtin_bit_cast(unsigned short, __float2bfloat16(f));
}

__device__ __forceinline__ void load8f(const float* p, float v[8]) {
    float4 a = *reinterpret_cast<const float4*>(p);
    float4 b = *reinterpret_cast<const float4*>(p + 4);
    v[0] = a.x; v[1] = a.y; v[2] = a.z; v[3] = a.w;
    v[4] = b.x; v[5] = b.y; v[6] = b.z; v[7] = b.w;
}
__device__ __forceinline__ void store8b(bf16* p, const float v[8]) {
    alignas(16) bf16 o[8];
#pragma unroll
    for (int i = 0; i < 8; ++i) o[i] = __float2bfloat16(v[i]);
    *reinterpret_cast<uint4*>(p) = *reinterpret_cast<const uint4*>(o);
}

// exact-GELU via Abramowitz-Stegun 7.1.26 erf (|err| < 1.5e-7)
__device__ __forceinline__ float gelu_erf(float v) {
    float z  = fabsf(v) * 0.70710678118654752f;
    float t  = __builtin_amdgcn_rcpf(1.f + 0.3275911f * z);
    float poly = t * (0.254829592f + t * (-0.284496736f + t * (1.421413741f
               + t * (-1.453152027f + t * 1.061405429f))));
    float erfz = 1.f - poly * __expf(-z * z);
    float erfv = copysignf(erfz, v);
    return 0.5f * v * (1.f + erfv);
}

// ---------------- Kernel 1: LayerNorm over channel dim of NCHW ----------------
__global__ __launch_bounds__(256) void ln_kernel(
    const float* __restrict__ x, const float* __restrict__ lw,
    const float* __restrict__ lb, bf16* __restrict__ y)
{
    int t  = blockIdx.x * 256 + threadIdx.x;   // [0, 131072)
    int b  = t >> 15;
    int hw = (t & 32767) * 2;
    size_t base = (size_t)b * CC * HW + hw;

    float s0 = 0.f, s1 = 0.f, q0 = 0.f, q1 = 0.f;
    for (int c = 0; c < CC; ++c) {
        float2 v = *reinterpret_cast<const float2*>(&x[base + (size_t)c * HW]);
        s0 += v.x; s1 += v.y; q0 += v.x * v.x; q1 += v.y * v.y;
    }
    float mu0 = s0 * (1.f / 96.f), mu1 = s1 * (1.f / 96.f);
    float rs0 = rsqrtf(q0 * (1.f / 96.f) - mu0 * mu0 + 1e-6f);
    float rs1 = rsqrtf(q1 * (1.f / 96.f) - mu1 * mu1 + 1e-6f);

    for (int c = 0; c < CC; ++c) {
        float2 v = *reinterpret_cast<const float2*>(&x[base + (size_t)c * HW]);
        float g = lw[c], be = lb[c];
        bf16 o[2];
        o[0] = __float2bfloat16((v.x - mu0) * rs0 * g + be);
        o[1] = __float2bfloat16((v.y - mu1) * rs1 * g + be);
        *reinterpret_cast<uint*>(&y[base + (size_t)c * HW]) = *reinterpret_cast<uint*>(o);
    }
}

// ---------------- conv1x1 via MFMA 16x16x32 bf16 ----------------
// GEMM: out[o][p] = sum_c W[o][c] * X[c][p].  A = W (M=COUT), B = X (N=positions).
// Block = 4 waves, tile M=COUT x N=128. Weights LDS [COUT][CIN+8] bf16 (A-frag =
// one aligned ds_read_b128). B-frags loaded straight global->VGPR (8 scalar loads,
// 16 consecutive positions/lane-group: coalesced, block covers full cachelines).
// Layouts (m89-verified): A[m=lane&15][k=quad*8+j]; B[k=quad*8+j][n=lane&15];
// D col=lane&15 (position), row=quad*4+reg (channel).
template <typename TI, typename TOT, int CIN, int COUT, bool GELU, bool HASRES>
__global__ __launch_bounds__(256) void conv1x1_mfma(
    const TI* __restrict__ in, const float* __restrict__ wgt,
    const float* __restrict__ bias, const float* __restrict__ resid,
    TOT* __restrict__ out)
{
    constexpr int CINP = CIN + 8;
    constexpr int MT   = COUT / 16;
    constexpr int KT   = CIN / 32;
    __shared__ unsigned short s_w[COUT * CINP];
    __shared__ float          s_b[COUT];

    const int tid  = threadIdx.x;
    const int lane = tid & 63;
    const int wave = tid >> 6;
    const int q    = lane >> 4;
    const int n    = lane & 15;

    const int pos0 = blockIdx.x * 128;
    const int b    = pos0 >> 16;
    const int hw0  = pos0 & 65535;

    // stage weights fp32 -> bf16 LDS, + bias
    constexpr int C4 = CIN / 4;
    for (int k = tid; k < COUT * C4; k += 256) {
        int o = k / C4, c4 = (k - o * C4) * 4;
        float4 w4 = *reinterpret_cast<const float4*>(&wgt[o * CIN + c4]);
        ushort4 pk = make_ushort4(f2bu(w4.x), f2bu(w4.y), f2bu(w4.z), f2bu(w4.w));
        *reinterpret_cast<ushort4*>(&s_w[o * CINP + c4]) = pk;
    }
    for (int k = tid; k < COUT; k += 256) s_b[k] = bias[k];
    __syncthreads();

    const TI* inb = in + (size_t)b * CIN * HW;
    const int p0  = hw0 + wave * 32 + n;
    const int p1  = p0 + 16;

    f32x4 acc[MT][2];
#pragma unroll
    for (int mt = 0; mt < MT; ++mt) {
        acc[mt][0] = {0.f, 0.f, 0.f, 0.f};
        acc[mt][1] = {0.f, 0.f, 0.f, 0.f};
    }

    for (int kt = 0; kt < KT; ++kt) {
        const int c0 = kt * 32 + q * 8;
        union { unsigned short u[8]; bf16x8 v; } bf0, bf1;
#pragma unroll
        for (int j = 0; j < 8; ++j) {
            const size_t rowo = (size_t)(c0 + j) * HW;
            if constexpr (__is_same(TI, float)) {
                bf0.u[j] = f2bu(inb[rowo + p0]);
                bf1.u[j] = f2bu(inb[rowo + p1]);
            } else {
                bf0.u[j] = *reinterpret_cast<const unsigned short*>(&inb[rowo + p0]);
                bf1.u[j] = *reinterpret_cast<const unsigned short*>(&inb[rowo + p1]);
            }
        }
#pragma unroll
        for (int mt = 0; mt < MT; ++mt) {
            union { unsigned short u[8]; bf16x8 v; } fa;
            *reinterpret_cast<uint4*>(fa.u) =
                *reinterpret_cast<const uint4*>(&s_w[(mt * 16 + n) * CINP + kt * 32 + q * 8]);
            acc[mt][0] = __builtin_amdgcn_mfma_f32_16x16x32_bf16(fa.v, bf0.v, acc[mt][0], 0, 0, 0);
            acc[mt][1] = __builtin_amdgcn_mfma_f32_16x16x32_bf16(fa.v, bf1.v, acc[mt][1], 0, 0, 0);
        }
    }

    const size_t obase = (size_t)b * COUT * HW;
#pragma unroll
    for (int mt = 0; mt < MT; ++mt) {
#pragma unroll
        for (int nt = 0; nt < 2; ++nt) {
            const int p = (nt == 0) ? p0 : p1;
#pragma unroll
            for (int r = 0; r < 4; ++r) {
                const int o = mt * 16 + q * 4 + r;
                float v = acc[mt][nt][r] + s_b[o];
                if constexpr (GELU) v = gelu_erf(v);
                const size_t idx = obase + (size_t)o * HW + p;
                if constexpr (HASRES) v += resid[idx];
                if constexpr (__is_same(TOT, float)) out[idx] = v;
                else                                 out[idx] = __float2bfloat16(v);
            }
        }
    }
}

// ---------------- Kernel 3: experts, register-window stencil ----------------
__device__ __forceinline__ void load_win24(const bf16* rowp, int w0, bool rowok,
                                           float win[24])
{
    const uint4 z = make_uint4(0u, 0u, 0u, 0u);
    const uint4* p = reinterpret_cast<const uint4*>(rowp + w0 - 8);
    uint4 c0 = (rowok && (w0 >= 8))   ? p[0] : z;
    uint4 c1 =  rowok                 ? p[1] : z;
    uint4 c2 = (rowok && (w0 <= 240)) ? p[2] : z;
    win[0]=lo2f(c0.x); win[1]=hi2f(c0.x); win[2]=lo2f(c0.y); win[3]=hi2f(c0.y);
    win[4]=lo2f(c0.z); win[5]=hi2f(c0.z); win[6]=lo2f(c0.w); win[7]=hi2f(c0.w);
    win[8]=lo2f(c1.x); win[9]=hi2f(c1.x); win[10]=lo2f(c1.y); win[11]=hi2f(c1.y);
    win[12]=lo2f(c1.z); win[13]=hi2f(c1.z); win[14]=lo2f(c1.w); win[15]=hi2f(c1.w);
    win[16]=lo2f(c2.x); win[17]=hi2f(c2.x); win[18]=lo2f(c2.y); win[19]=hi2f(c2.y);
    win[20]=lo2f(c2.z); win[21]=hi2f(c2.z); win[22]=lo2f(c2.w); win[23]=hi2f(c2.w);
}
__device__ __forceinline__ void apply3(const float wk[3], int dil,
                                       const float win[24], float acc[8])
{
#pragma unroll
    for (int kw = 0; kw < 3; ++kw) {
        float wv = wk[kw];
        int d = (kw - 1) * dil;
#pragma unroll
        for (int o = 0; o < 8; ++o) acc[o] += wv * win[o + 8 + d];
    }
}
__device__ __forceinline__ void apply5(const float wk[5],
                                       const float win[24], float acc[8])
{
#pragma unroll
    for (int kw = 0; kw < 5; ++kw) {
        float wv = wk[kw];
        int d = (kw - 2) * 3;
#pragma unroll
        for (int o = 0; o < 8; ++o) acc[o] += wv * win[o + 8 + d];
    }
}

__global__ __launch_bounds__(256) void experts_kernel(
    const bf16* __restrict__ xn, const bf16* __restrict__ t0,
    const float* __restrict__ w0, const float* __restrict__ b0,
    const float* __restrict__ w1, const float* __restrict__ b1,
    const float* __restrict__ w2, const float* __restrict__ b2,
    const float* __restrict__ sw, const float* __restrict__ prompt,
    bf16* __restrict__ xa)
{
    const int tid = threadIdx.x;
    const int wg  = tid & 31;
    const int r   = tid >> 5;
    const int bid = blockIdx.x;
    const int h0  = (bid & 31) * 8;
    const int bc  = bid >> 5;
    const int b   = bc / 96;
    const int c   = bc - b * 96;
    const int h   = h0 + r;
    const int w0p = wg * 8;
    const size_t pbase = (size_t)bc * HW;

    float wk0[9], wk1[9], wk2[25];
#pragma unroll
    for (int i = 0; i < 9; ++i)  wk0[i] = w0[c * 9 + i];
#pragma unroll
    for (int i = 0; i < 9; ++i)  wk1[i] = w1[c * 9 + i];
#pragma unroll
    for (int i = 0; i < 25; ++i) wk2[i] = w2[c * 25 + i];

    float acc0[8], acc1[8], acc2[8];
    {
        float bb0 = b0[c], bb1 = b1[c], bb2 = b2[c];
#pragma unroll
        for (int o = 0; o < 8; ++o) { acc0[o] = bb0; acc1[o] = bb1; acc2[o] = bb2; }
    }

    const bf16* xp = xn + pbase;
    const bf16* tp = t0 + pbase;
    float win[24];

    {
        int hh = h - 6; bool ok = (unsigned)hh < 256u;
        load_win24(xp + hh * WID, w0p, ok, win); apply5(&wk2[0],  win, acc2);
    }
    {
        int hh = h - 3; bool ok = (unsigned)hh < 256u;
        load_win24(xp + hh * WID, w0p, ok, win); apply5(&wk2[5],  win, acc2);
    }
    {
        int hh = h - 2; bool ok = (unsigned)hh < 256u;
        load_win24(xp + hh * WID, w0p, ok, win); apply3(&wk1[0], 2, win, acc1);
    }
    {
        load_win24(xp + h * WID, w0p, true, win);
        apply3(&wk1[3], 2, win, acc1); apply5(&wk2[10], win, acc2);
    }
    {
        int hh = h + 2; bool ok = (unsigned)hh < 256u;
        load_win24(xp + hh * WID, w0p, ok, win); apply3(&wk1[6], 2, win, acc1);
    }
    {
        int hh = h + 3; bool ok = (unsigned)hh < 256u;
        load_win24(xp + hh * WID, w0p, ok, win); apply5(&wk2[15], win, acc2);
    }
    {
        int hh = h + 6; bool ok = (unsigned)hh < 256u;
        load_win24(xp + hh * WID, w0p, ok, win); apply5(&wk2[20], win, acc2);
    }
    {
        int hh = h - 1; bool ok = (unsigned)hh < 256u;
        load_win24(tp + hh * WID, w0p, ok, win); apply3(&wk0[0], 1, win, acc0);
    }
    {
        load_win24(tp + h * WID, w0p, true, win); apply3(&wk0[3], 1, win, acc0);
    }
    {
        int hh = h + 1; bool ok = (unsigned)hh < 256u;
        load_win24(tp + hh * WID, w0p, ok, win); apply3(&wk0[6], 1, win, acc0);
    }

    float s0 = sw[b * 3 + 0], s1 = sw[b * 3 + 1], s2 = sw[b * 3 + 2];
    float pr = 1.f + prompt[b * 96 + c];
    float ov[8];
#pragma unroll
    for (int o = 0; o < 8; ++o)
        ov[o] = (s0 * acc0[o] + s1 * acc1[o] + s2 * acc2[o]) * pr;
    store8b(&xa[pbase + h * WID + w0p], ov);
}

// ---------------- launch ----------------
extern "C" void kernel_launch(void* const* d_in, const int* in_sizes, int n_in,
                              void* d_out, int out_size, void* d_ws, size_t ws_size,
                              hipStream_t stream)
{
    const float* x       = (const float*)d_in[0];
    const float* prompt  = (const float*)d_in[1];
    const float* sw      = (const float*)d_in[2];
    const float* ln_w    = (const float*)d_in[3];
    const float* ln_b    = (const float*)d_in[4];
    const float* e0_pw_w = (const float*)d_in[5];
    const float* e0_pw_b = (const float*)d_in[6];
    const float* e0_dw_w = (const float*)d_in[7];
    const float* e0_dw_b = (const float*)d_in[8];
    const float* e1_dw_w = (const float*)d_in[9];
    const float* e1_dw_b = (const float*)d_in[10];
    const float* e2_dw_w = (const float*)d_in[11];
    const float* e2_dw_b = (const float*)d_in[12];
    const float* proj_w  = (const float*)d_in[13];
    const float* proj_b  = (const float*)d_in[14];
    const float* ffn1_w  = (const float*)d_in[15];
    const float* ffn1_b  = (const float*)d_in[16];
    const float* ffn2_w  = (const float*)d_in[17];
    const float* ffn2_b  = (const float*)d_in[18];

    float* out = (float*)d_out;                 // x1 lives here fp32 between k4..k6
    bf16*  ws  = (bf16*)d_ws;
    bf16*  A   = ws;                 // xn  bf16 (48 MB)
    bf16*  Bt  = ws + S_ELEMS;       // t0  bf16 (48 MB)
    bf16*  Cx  = ws + 2 * S_ELEMS;   // xa  bf16 (48 MB)  -> peak ws = 144 MB
    bf16*  E   = ws;                 // h (192 ch) bf16 (96 MB), reuses A+Bt once dead

    // 1) xn = LayerNorm_c(x)
    ln_kernel<<<512, 256, 0, stream>>>(x, ln_w, ln_b, A);
    // 2) t0 = conv1x1(xn, e0_pw)
    conv1x1_mfma<bf16, bf16, 96, 96, false, false>
        <<<2048, 256, 0, stream>>>(A, e0_pw_w, e0_pw_b, nullptr, Bt);
    // 3) xa = (s0*dw3(t0) + s1*dw3d2(xn) + s2*dw5d3(xn)) * (1+prompt)
    experts_kernel<<<12288, 256, 0, stream>>>(A, Bt, e0_dw_w, e0_dw_b, e1_dw_w, e1_dw_b,
                                              e2_dw_w, e2_dw_b, sw, prompt, Cx);
    // 4) x1 = x + conv1x1(xa, proj)  -> d_out (fp32)
    conv1x1_mfma<bf16, float, 96, 96, false, true>
        <<<2048, 256, 0, stream>>>(Cx, proj_w, proj_b, x, out);
    // 5) h = gelu(conv1x1(x1, ffn1)) -> E (bf16)
    conv1x1_mfma<float, bf16, 96, 192, true, false>
        <<<2048, 256, 0, stream>>>(out, ffn1_w, ffn1_b, nullptr, E);
    // 6) out = x1 + conv1x1(h, ffn2) -> d_out (in-place, per-thread same-address RMW)
    conv1x1_mfma<bf16, float, 192, 96, false, true>
        <<<2048, 256, 0, stream>>>(E, ffn2_w, ffn2_b, out, out);
}